// Round 2
// baseline (28078.308 us; speedup 1.0000x reference)
//
#include <hip/hip_runtime.h>
#include <hip/hip_bf16.h>

#define TT 2048
#define DIM 1024
#define HFF 8192
#define NBATCH 4
#define NWG 64
#define THRESH 0.05f

typedef __bf16 bf16x8 __attribute__((ext_vector_type(8)));
typedef float f32x4 __attribute__((ext_vector_type(4)));

__device__ __forceinline__ unsigned short f2bf(float f) {
    __hip_bfloat16 h = __float2bfloat16(f);
    return __builtin_bit_cast(unsigned short, h);
}
__device__ __forceinline__ float bf2f(unsigned short u) {
    return __bfloat162float(__builtin_bit_cast(__hip_bfloat16, u));
}
__device__ __forceinline__ bf16x8 ldf(const unsigned short* p) {
    return *reinterpret_cast<const bf16x8*>(p);
}

// ---------------- mask dtype probe: 1 = int32 mask, 0 = uint8 mask ----------
__global__ void maskprobe_k(const unsigned int* mask_words, int* flag) {
    __shared__ int allok;
    if (threadIdx.x == 0) allok = 1;
    __syncthreads();
    int ok = 1;
    for (int i = 0; i < 16; ++i) {
        unsigned int w = mask_words[threadIdx.x * 16 + i];
        if (w > 1u) ok = 0;
    }
    if (!ok) atomicAnd(&allok, 0);
    __syncthreads();
    if (threadIdx.x == 0) flag[0] = allok;
}

// ---------------- w_eff = syn_w * mask  -> bf16 ----------------
__global__ void weff_k(const float* __restrict__ synw, const void* __restrict__ mask,
                       const int* __restrict__ flag, unsigned short* __restrict__ dst) {
    const int isInt = flag[0];
    const int n = DIM * DIM;
    for (int i = blockIdx.x * 256 + threadIdx.x; i < n; i += gridDim.x * 256) {
        bool m;
        if (isInt) m = ((const int*)mask)[i] != 0;
        else       m = ((const unsigned char*)mask)[i] != 0;
        dst[i] = f2bf(m ? synw[i] : 0.f);
    }
}

// ---------------- f32 -> bf16 convert ----------------
__global__ void conv_k(const float* __restrict__ src, unsigned short* __restrict__ dst, int n) {
    for (int i = blockIdx.x * 256 + threadIdx.x; i < n; i += gridDim.x * 256)
        dst[i] = f2bf(src[i]);
}

// ---------------- f32 -> bf16 hi/lo split ----------------
__global__ void split_k(const float* __restrict__ src, unsigned short* __restrict__ hi,
                        unsigned short* __restrict__ lo, int n) {
    for (int i = blockIdx.x * 256 + threadIdx.x; i < n; i += gridDim.x * 256) {
        float v = src[i];
        unsigned short h = f2bf(v);
        hi[i] = h;
        lo[i] = f2bf(v - bf2f(h));
    }
}

// ---------------- spike bit expansion: u32 bits -> bf16 {0,1} ----------------
// spk layout: [b][t32][d]  (4 x 64 x 1024 u32); sbf layout: [b][t][d]
__global__ void spkexp_k(const unsigned int* __restrict__ spk, unsigned short* __restrict__ sbf) {
    const int i = blockIdx.x * 256 + threadIdx.x;   // 4*64*1024 words
    const unsigned int w = spk[i];
    const int d = i & 1023, t32 = (i >> 10) & 63, b = i >> 16;
    const size_t base = ((size_t)b * TT + (size_t)t32 * 32) * DIM + d;
    #pragma unroll
    for (int j = 0; j < 32; ++j)
        sbf[base + (size_t)j * DIM] = ((w >> j) & 1u) ? (unsigned short)0x3F80 : (unsigned short)0;
}

// ---------------- rmsnorm; SPLIT: also emit lo residual ----------------
template <bool SPLIT>
__global__ void rms_k(const float* __restrict__ xin, const float* __restrict__ w,
                      unsigned short* __restrict__ hi, unsigned short* __restrict__ lo) {
    const int row = blockIdx.x;
    const int tid = threadIdx.x;
    const float4 xv = *reinterpret_cast<const float4*>(xin + (size_t)row * DIM + tid * 4);
    float ss = xv.x * xv.x + xv.y * xv.y + xv.z * xv.z + xv.w * xv.w;
    #pragma unroll
    for (int m = 1; m <= 32; m <<= 1) ss += __shfl_xor(ss, m);
    __shared__ float red[5];
    if ((tid & 63) == 0) red[tid >> 6] = ss;
    __syncthreads();
    if (tid == 0) {
        float s = red[0] + red[1] + red[2] + red[3];
        red[4] = 1.f / sqrtf(s * (1.f / DIM) + 1e-6f);
    }
    __syncthreads();
    const float scale = red[4];
    const float wv[4] = {w[tid*4], w[tid*4+1], w[tid*4+2], w[tid*4+3]};
    const float xa[4] = {xv.x, xv.y, xv.z, xv.w};
    #pragma unroll
    for (int i = 0; i < 4; ++i) {
        float v = xa[i] * scale * wv[i];
        unsigned short h = f2bf(v);
        hi[(size_t)row * DIM + tid * 4 + i] = h;
        if constexpr (SPLIT) lo[(size_t)row * DIM + tid * 4 + i] = f2bf(v - bf2f(h));
    }
}

// ---------------- generic MFMA GEMM: C = A @ B^T, A (M,K) bf16, B (N,K) bf16
// EPI 0: U write (hilo A/B; out f32 (T,B,D) + liq_b)    [single B]
// EPI 1: gated residual: x2 = x + acc1*sigmoid(acc2+gb) [dual B]
// EPI 2: swiglu: hbf = bf16(silu(acc1)*acc2)            [dual B]
// EPI 3: out = x2 + acc1                                [single B]
template <int EPI>
__global__ __launch_bounds__(256, 1) void gemm_k(
    const unsigned short* __restrict__ A,  const unsigned short* __restrict__ Alo,
    const unsigned short* __restrict__ B1, const unsigned short* __restrict__ B1lo,
    const unsigned short* __restrict__ B2,
    const float* __restrict__ aux1, const float* __restrict__ aux2,
    float* __restrict__ outf, unsigned short* __restrict__ outbf,
    int M, int N, int K) {
    constexpr bool HILO = (EPI == 0);
    constexpr bool DUAL = (EPI == 1 || EPI == 2);
    const int lane = threadIdx.x & 63;
    const int wv = threadIdx.x >> 6;
    const int l15 = lane & 15, l4 = lane >> 4;
    const long row0 = (long)blockIdx.y * 128 + (wv >> 1) * 64;
    const long col0 = (long)blockIdx.x * 128 + (wv & 1) * 64;
    long aoff[4], boff[4];
    #pragma unroll
    for (int i = 0; i < 4; ++i) {
        aoff[i] = (row0 + i * 16 + l15) * (long)K + l4 * 8;
        boff[i] = (col0 + i * 16 + l15) * (long)K + l4 * 8;
    }
    f32x4 acc[4][4];
    f32x4 acc2[DUAL ? 4 : 1][DUAL ? 4 : 1];
    #pragma unroll
    for (int i = 0; i < 4; ++i)
        #pragma unroll
        for (int j = 0; j < 4; ++j) {
            acc[i][j] = (f32x4){0.f, 0.f, 0.f, 0.f};
            if constexpr (DUAL) acc2[i][j] = (f32x4){0.f, 0.f, 0.f, 0.f};
        }
    for (int kk = 0; kk < K; kk += 32) {
        bf16x8 af[4], bf_[4], al[4], bl[4], b2f[4];
        #pragma unroll
        for (int i = 0; i < 4; ++i) {
            af[i] = ldf(A + aoff[i] + kk);
            bf_[i] = ldf(B1 + boff[i] + kk);
            if constexpr (HILO) {
                al[i] = ldf(Alo + aoff[i] + kk);
                bl[i] = ldf(B1lo + boff[i] + kk);
            }
            if constexpr (DUAL) b2f[i] = ldf(B2 + boff[i] + kk);
        }
        #pragma unroll
        for (int i = 0; i < 4; ++i)
            #pragma unroll
            for (int j = 0; j < 4; ++j) {
                acc[i][j] = __builtin_amdgcn_mfma_f32_16x16x32_bf16(af[i], bf_[j], acc[i][j], 0, 0, 0);
                if constexpr (HILO) {
                    acc[i][j] = __builtin_amdgcn_mfma_f32_16x16x32_bf16(af[i], bl[j], acc[i][j], 0, 0, 0);
                    acc[i][j] = __builtin_amdgcn_mfma_f32_16x16x32_bf16(al[i], bf_[j], acc[i][j], 0, 0, 0);
                }
                if constexpr (DUAL)
                    acc2[i][j] = __builtin_amdgcn_mfma_f32_16x16x32_bf16(af[i], b2f[j], acc2[i][j], 0, 0, 0);
            }
    }
    #pragma unroll
    for (int i = 0; i < 4; ++i) {
        #pragma unroll
        for (int r = 0; r < 4; ++r) {
            const long row = row0 + i * 16 + l4 * 4 + r;
            #pragma unroll
            for (int j = 0; j < 4; ++j) {
                const long col = col0 + j * 16 + l15;
                float v = acc[i][j][r];
                if constexpr (EPI == 0) {
                    int m = (int)row;
                    int bb = m >> 11, tt = m & 2047;
                    outf[((size_t)(tt * NBATCH + bb)) * DIM + col] = v + aux1[col];
                } else if constexpr (EPI == 1) {
                    size_t idx = (size_t)row * N + col;
                    float g = acc2[i][j][r] + aux2[col];
                    outf[idx] = aux1[idx] + v * (1.f / (1.f + expf(-g)));
                } else if constexpr (EPI == 2) {
                    size_t idx = (size_t)row * N + col;
                    float u = acc2[i][j][r];
                    outbf[idx] = f2bf((v / (1.f + expf(-v))) * u);
                } else {
                    size_t idx = (size_t)row * N + col;
                    outf[idx] = aux1[idx] + v;
                }
            }
        }
    }
}

// ---------------- liquid recurrence + PLIF, 64 persistent WGs ----------------
// WG wg owns dims [wg*16, wg*16+16); Wrec slice lives in registers.
// thread t: d_local = t>>4 (0..15), kp = t&15, k-range = [kp*64, kp*64+64)
// Barrier: distributed per-WG monotone flags, wave-0 64-lane vector poll.
__global__ __launch_bounds__(256, 1) void recur_k(
    const float* __restrict__ wrec, const float* __restrict__ U,
    const float* __restrict__ liqtau, const float* __restrict__ plifw,
    float* __restrict__ hg, int* __restrict__ flags, unsigned int* __restrict__ spk) {
    const int tid = threadIdx.x;
    const int wg = blockIdx.x;
    const int d_local = tid >> 4;
    const int kp = tid & 15;
    const int gdim = wg * 16 + d_local;
    const int lane = tid & 63;
    const int wave = tid >> 6;

    float wreg[64];
    {
        const float* wr = wrec + (size_t)gdim * DIM + kp * 64;
        #pragma unroll
        for (int j = 0; j < 64; j += 4) {
            float4 w4 = *reinterpret_cast<const float4*>(wr + j);
            wreg[j] = w4.x; wreg[j + 1] = w4.y; wreg[j + 2] = w4.z; wreg[j + 3] = w4.w;
        }
    }

    // skewed h staging: [b][k] at b*1088 + (k>>6)*68 + (k&63)
    __shared__ float hl[4 * 1088];
    for (int i = tid; i < 4 * 1088; i += 256) hl[i] = 0.f;

    const float decay = 1.f / (1.f + expf(-plifw[0]));
    const bool lead = (kp == 0);
    float hreg[4] = {0.f, 0.f, 0.f, 0.f};
    float vreg[4] = {0.f, 0.f, 0.f, 0.f};
    unsigned int smask[4] = {0u, 0u, 0u, 0u};
    float tauv = 1.f;
    if (lead) {
        float lt = liqtau[gdim];
        tauv = (lt > 20.f) ? lt : log1pf(expf(lt));
    }
    __syncthreads();

    const float* hb = hl + kp * 68;
    for (int t = 0; t < TT; ++t) {
        // U prefetch: issue at top of step; lands under the FMA loop.
        float uv[4];
        if (lead) {
            #pragma unroll
            for (int b = 0; b < 4; ++b)
                uv[b] = U[((size_t)t * NBATCH + b) * DIM + gdim];
        }
        float a0 = 0.f, a1 = 0.f, a2 = 0.f, a3 = 0.f;
        #pragma unroll
        for (int j4 = 0; j4 < 16; ++j4) {
            const int ko = j4 * 4;
            const float4 h0 = *reinterpret_cast<const float4*>(hb + ko);
            const float4 h1 = *reinterpret_cast<const float4*>(hb + 1088 + ko);
            const float4 h2 = *reinterpret_cast<const float4*>(hb + 2176 + ko);
            const float4 h3 = *reinterpret_cast<const float4*>(hb + 3264 + ko);
            a0 = fmaf(wreg[ko], h0.x, a0); a0 = fmaf(wreg[ko+1], h0.y, a0);
            a0 = fmaf(wreg[ko+2], h0.z, a0); a0 = fmaf(wreg[ko+3], h0.w, a0);
            a1 = fmaf(wreg[ko], h1.x, a1); a1 = fmaf(wreg[ko+1], h1.y, a1);
            a1 = fmaf(wreg[ko+2], h1.z, a1); a1 = fmaf(wreg[ko+3], h1.w, a1);
            a2 = fmaf(wreg[ko], h2.x, a2); a2 = fmaf(wreg[ko+1], h2.y, a2);
            a2 = fmaf(wreg[ko+2], h2.z, a2); a2 = fmaf(wreg[ko+3], h2.w, a2);
            a3 = fmaf(wreg[ko], h3.x, a3); a3 = fmaf(wreg[ko+1], h3.y, a3);
            a3 = fmaf(wreg[ko+2], h3.z, a3); a3 = fmaf(wreg[ko+3], h3.w, a3);
        }
        #pragma unroll
        for (int m = 1; m <= 8; m <<= 1) {
            a0 += __shfl_xor(a0, m); a1 += __shfl_xor(a1, m);
            a2 += __shfl_xor(a2, m); a3 += __shfl_xor(a3, m);
        }
        if (lead) {
            const float accs[4] = {a0, a1, a2, a3};
            #pragma unroll
            for (int b = 0; b < 4; ++b) {
                float pre = accs[b] + uv[b];
                float th = tanhf(pre);
                float hn = hreg[b] + (th - hreg[b]) / tauv;
                hreg[b] = hn;
                float v = vreg[b] + decay * (hn - vreg[b]);
                float s = ((v - THRESH) > 0.f) ? 1.f : 0.f;
                vreg[b] = v - s * THRESH;
                smask[b] |= (s > 0.f ? 1u : 0u) << (t & 31);
                __hip_atomic_store(&hg[(size_t)(t & 1) * 4096 + b * DIM + gdim], hn,
                                   __ATOMIC_RELAXED, __HIP_MEMORY_SCOPE_AGENT);
            }
            if ((t & 31) == 31) {
                #pragma unroll
                for (int b = 0; b < 4; ++b) {
                    spk[b * 65536 + (t >> 5) * 1024 + gdim] = smask[b];
                    smask[b] = 0u;
                }
            }
        }
        if (t == TT - 1) break;
        __syncthreads();  // drains vmcnt per wave -> all h stores at coherence point
        if (tid == 0)
            __hip_atomic_store(&flags[wg], t + 1, __ATOMIC_RELEASE, __HIP_MEMORY_SCOPE_AGENT);
        if (wave == 0) {
            // 64 lanes poll all 64 WG flags with one vector load per round;
            // dependent-load latency (~600 cyc) naturally paces the loop.
            while (true) {
                int f = __hip_atomic_load(&flags[lane], __ATOMIC_RELAXED, __HIP_MEMORY_SCOPE_AGENT);
                if (__all(f >= t + 1)) break;
            }
        }
        __syncthreads();
        __threadfence();  // acquire side of the flag handshake
        {
            const float* src = hg + (size_t)(t & 1) * 4096;
            #pragma unroll
            for (int j = 0; j < 16; ++j) {
                int g = tid + j * 256;
                float v = __hip_atomic_load(&src[g], __ATOMIC_RELAXED, __HIP_MEMORY_SCOPE_AGENT);
                int b = g >> 10, k = g & 1023;
                hl[b * 1088 + (k >> 6) * 68 + (k & 63)] = v;
            }
        }
        __syncthreads();
    }
}

extern "C" void kernel_launch(void* const* d_in, const int* in_sizes, int n_in,
                              void* d_out, int out_size, void* d_ws, size_t ws_size,
                              hipStream_t stream) {
    (void)in_sizes; (void)n_in; (void)out_size; (void)ws_size;
    const float* x     = (const float*)d_in[0];
    const float* ln1   = (const float*)d_in[1];
    const float* win   = (const float*)d_in[2];
    const float* wrec  = (const float*)d_in[3];
    const float* liqb  = (const float*)d_in[4];
    const float* liqtau= (const float*)d_in[5];
    const float* plifw = (const float*)d_in[6];
    const float* synw  = (const float*)d_in[7];
    const float* gatew = (const float*)d_in[8];
    const float* gateb = (const float*)d_in[9];
    const float* ln2   = (const float*)d_in[10];
    const float* wgp   = (const float*)d_in[11];
    const float* wup   = (const float*)d_in[12];
    const float* wdp   = (const float*)d_in[13];
    const void*  mask  = d_in[14];
    float* dout = (float*)d_out;
    char* ws = (char*)d_ws;
    const size_t MB = (size_t)1 << 20;

    unsigned short* winh  = (unsigned short*)(ws + 0 * MB);
    unsigned short* winl  = (unsigned short*)(ws + 2 * MB);
    unsigned short* weffb = (unsigned short*)(ws + 4 * MB);
    unsigned short* gatewb= (unsigned short*)(ws + 6 * MB);
    unsigned short* wgb   = (unsigned short*)(ws + 8 * MB);
    unsigned short* wub   = (unsigned short*)(ws + 24 * MB);
    unsigned short* wdb   = (unsigned short*)(ws + 40 * MB);
    unsigned short* ahi   = (unsigned short*)(ws + 56 * MB);   // reused as y_bf
    unsigned short* alo   = (unsigned short*)(ws + 72 * MB);
    float*          Ubuf  = (float*)(ws + 88 * MB);            // reused as hff chunk
    unsigned short* hffb  = (unsigned short*)(ws + 88 * MB);
    unsigned short* sbf   = (unsigned short*)(ws + 120 * MB);
    float*          x2    = (float*)(ws + 136 * MB);
    float*          hgb   = (float*)(ws + 168 * MB);           // 32 KB
    int*            flags = (int*)(ws + 168 * MB + 64 * 1024);
    int*            flag  = (int*)(ws + 168 * MB + 80 * 1024);
    unsigned int*   spk   = (unsigned int*)(ws + 169 * MB);    // 1 MB

    hipMemsetAsync(flags, 0, NWG * sizeof(int), stream);
    maskprobe_k<<<1, 256, 0, stream>>>((const unsigned int*)mask, flag);
    weff_k<<<1024, 256, 0, stream>>>(synw, mask, flag, weffb);
    split_k<<<1024, 256, 0, stream>>>(win, winh, winl, DIM * DIM);
    conv_k<<<1024, 256, 0, stream>>>(gatew, gatewb, DIM * DIM);
    conv_k<<<2048, 256, 0, stream>>>(wgp, wgb, HFF * DIM);
    conv_k<<<2048, 256, 0, stream>>>(wup, wub, HFF * DIM);
    conv_k<<<2048, 256, 0, stream>>>(wdp, wdb, DIM * HFF);

    rms_k<true><<<NBATCH * TT, 256, 0, stream>>>(x, ln1, ahi, alo);
    gemm_k<0><<<dim3(DIM / 128, (NBATCH * TT) / 128), 256, 0, stream>>>(
        ahi, alo, winh, winl, nullptr, liqb, nullptr, Ubuf, nullptr,
        NBATCH * TT, DIM, DIM);

    recur_k<<<NWG, 256, 0, stream>>>(wrec, Ubuf, liqtau, plifw, hgb, flags, spk);
    spkexp_k<<<(NBATCH * 64 * 1024) / 256, 256, 0, stream>>>(spk, sbf);

    gemm_k<1><<<dim3(DIM / 128, (NBATCH * TT) / 128), 256, 0, stream>>>(
        sbf, nullptr, weffb, nullptr, gatewb, x, gateb, x2, nullptr,
        NBATCH * TT, DIM, DIM);

    rms_k<false><<<NBATCH * TT, 256, 0, stream>>>(x2, ln2, ahi, nullptr);

    const int CH = 2048;  // FFN row-chunk to bound hff scratch to 32 MB
    for (int c = 0; c < (NBATCH * TT) / CH; ++c) {
        const size_t ro = (size_t)c * CH;
        gemm_k<2><<<dim3(HFF / 128, CH / 128), 256, 0, stream>>>(
            ahi + ro * DIM, nullptr, wgb, nullptr, wub, nullptr, nullptr,
            nullptr, hffb, CH, HFF, DIM);
        gemm_k<3><<<dim3(DIM / 128, CH / 128), 256, 0, stream>>>(
            hffb, nullptr, wdb, nullptr, nullptr, x2 + ro * DIM, nullptr,
            dout + ro * DIM, nullptr, CH, DIM, HFF);
    }
}

// Round 5
// 11779.539 us; speedup vs baseline: 2.3837x; 2.3837x over previous
//
#include <hip/hip_runtime.h>
#include <hip/hip_bf16.h>

#define TT 2048
#define DIM 1024
#define HFF 8192
#define NBATCH 4
#define PWG 32
#define THRESH 0.05f

typedef __bf16 bf16x8 __attribute__((ext_vector_type(8)));
typedef float f32x4 __attribute__((ext_vector_type(4)));

__device__ __forceinline__ unsigned short f2bf(float f) {
    __hip_bfloat16 h = __float2bfloat16(f);
    return __builtin_bit_cast(unsigned short, h);
}
__device__ __forceinline__ float bf2f(unsigned short u) {
    return __bfloat162float(__builtin_bit_cast(__hip_bfloat16, u));
}
__device__ __forceinline__ bf16x8 ldf(const unsigned short* p) {
    return *reinterpret_cast<const bf16x8*>(p);
}

// ---------------- mask dtype probe: 1 = int32 mask, 0 = uint8 mask ----------
__global__ void maskprobe_k(const unsigned int* mask_words, int* flag) {
    __shared__ int allok;
    if (threadIdx.x == 0) allok = 1;
    __syncthreads();
    int ok = 1;
    for (int i = 0; i < 16; ++i) {
        unsigned int w = mask_words[threadIdx.x * 16 + i];
        if (w > 1u) ok = 0;
    }
    if (!ok) atomicAnd(&allok, 0);
    __syncthreads();
    if (threadIdx.x == 0) flag[0] = allok;
}

// ---------------- w_eff = syn_w * mask  -> bf16 ----------------
__global__ void weff_k(const float* __restrict__ synw, const void* __restrict__ mask,
                       const int* __restrict__ flag, unsigned short* __restrict__ dst) {
    const int isInt = flag[0];
    const int n = DIM * DIM;
    for (int i = blockIdx.x * 256 + threadIdx.x; i < n; i += gridDim.x * 256) {
        bool m;
        if (isInt) m = ((const int*)mask)[i] != 0;
        else       m = ((const unsigned char*)mask)[i] != 0;
        dst[i] = f2bf(m ? synw[i] : 0.f);
    }
}

// ---------------- f32 -> bf16 convert ----------------
__global__ void conv_k(const float* __restrict__ src, unsigned short* __restrict__ dst, int n) {
    for (int i = blockIdx.x * 256 + threadIdx.x; i < n; i += gridDim.x * 256)
        dst[i] = f2bf(src[i]);
}

// ---------------- f32 -> bf16 hi/lo split ----------------
__global__ void split_k(const float* __restrict__ src, unsigned short* __restrict__ hi,
                        unsigned short* __restrict__ lo, int n) {
    for (int i = blockIdx.x * 256 + threadIdx.x; i < n; i += gridDim.x * 256) {
        float v = src[i];
        unsigned short h = f2bf(v);
        hi[i] = h;
        lo[i] = f2bf(v - bf2f(h));
    }
}

// ---------------- spike bit expansion: u32 bits -> bf16 {0,1} ----------------
__global__ void spkexp_k(const unsigned int* __restrict__ spk, unsigned short* __restrict__ sbf) {
    const int i = blockIdx.x * 256 + threadIdx.x;   // 4*64*1024 words
    const unsigned int w = spk[i];
    const int d = i & 1023, t32 = (i >> 10) & 63, b = i >> 16;
    const size_t base = ((size_t)b * TT + (size_t)t32 * 32) * DIM + d;
    #pragma unroll
    for (int j = 0; j < 32; ++j)
        sbf[base + (size_t)j * DIM] = ((w >> j) & 1u) ? (unsigned short)0x3F80 : (unsigned short)0;
}

// ---------------- rmsnorm; SPLIT: also emit lo residual ----------------
template <bool SPLIT>
__global__ void rms_k(const float* __restrict__ xin, const float* __restrict__ w,
                      unsigned short* __restrict__ hi, unsigned short* __restrict__ lo) {
    const int row = blockIdx.x;
    const int tid = threadIdx.x;
    const float4 xv = *reinterpret_cast<const float4*>(xin + (size_t)row * DIM + tid * 4);
    float ss = xv.x * xv.x + xv.y * xv.y + xv.z * xv.z + xv.w * xv.w;
    #pragma unroll
    for (int m = 1; m <= 32; m <<= 1) ss += __shfl_xor(ss, m);
    __shared__ float red[5];
    if ((tid & 63) == 0) red[tid >> 6] = ss;
    __syncthreads();
    if (tid == 0) {
        float s = red[0] + red[1] + red[2] + red[3];
        red[4] = 1.f / sqrtf(s * (1.f / DIM) + 1e-6f);
    }
    __syncthreads();
    const float scale = red[4];
    const float wv[4] = {w[tid*4], w[tid*4+1], w[tid*4+2], w[tid*4+3]};
    const float xa[4] = {xv.x, xv.y, xv.z, xv.w};
    #pragma unroll
    for (int i = 0; i < 4; ++i) {
        float v = xa[i] * scale * wv[i];
        unsigned short h = f2bf(v);
        hi[(size_t)row * DIM + tid * 4 + i] = h;
        if constexpr (SPLIT) lo[(size_t)row * DIM + tid * 4 + i] = f2bf(v - bf2f(h));
    }
}

// ---------------- generic MFMA GEMM: C = A @ B^T ----------------
template <int EPI>
__global__ __launch_bounds__(256, 1) void gemm_k(
    const unsigned short* __restrict__ A,  const unsigned short* __restrict__ Alo,
    const unsigned short* __restrict__ B1, const unsigned short* __restrict__ B1lo,
    const unsigned short* __restrict__ B2,
    const float* __restrict__ aux1, const float* __restrict__ aux2,
    float* __restrict__ outf, unsigned short* __restrict__ outbf,
    int M, int N, int K) {
    constexpr bool HILO = (EPI == 0);
    constexpr bool DUAL = (EPI == 1 || EPI == 2);
    const int lane = threadIdx.x & 63;
    const int wv = threadIdx.x >> 6;
    const int l15 = lane & 15, l4 = lane >> 4;
    const long row0 = (long)blockIdx.y * 128 + (wv >> 1) * 64;
    const long col0 = (long)blockIdx.x * 128 + (wv & 1) * 64;
    long aoff[4], boff[4];
    #pragma unroll
    for (int i = 0; i < 4; ++i) {
        aoff[i] = (row0 + i * 16 + l15) * (long)K + l4 * 8;
        boff[i] = (col0 + i * 16 + l15) * (long)K + l4 * 8;
    }
    f32x4 acc[4][4];
    f32x4 acc2[DUAL ? 4 : 1][DUAL ? 4 : 1];
    #pragma unroll
    for (int i = 0; i < 4; ++i)
        #pragma unroll
        for (int j = 0; j < 4; ++j) {
            acc[i][j] = (f32x4){0.f, 0.f, 0.f, 0.f};
            if constexpr (DUAL) acc2[i][j] = (f32x4){0.f, 0.f, 0.f, 0.f};
        }
    for (int kk = 0; kk < K; kk += 32) {
        bf16x8 af[4], bf_[4], al[4], bl[4], b2f[4];
        #pragma unroll
        for (int i = 0; i < 4; ++i) {
            af[i] = ldf(A + aoff[i] + kk);
            bf_[i] = ldf(B1 + boff[i] + kk);
            if constexpr (HILO) {
                al[i] = ldf(Alo + aoff[i] + kk);
                bl[i] = ldf(B1lo + boff[i] + kk);
            }
            if constexpr (DUAL) b2f[i] = ldf(B2 + boff[i] + kk);
        }
        #pragma unroll
        for (int i = 0; i < 4; ++i)
            #pragma unroll
            for (int j = 0; j < 4; ++j) {
                acc[i][j] = __builtin_amdgcn_mfma_f32_16x16x32_bf16(af[i], bf_[j], acc[i][j], 0, 0, 0);
                if constexpr (HILO) {
                    acc[i][j] = __builtin_amdgcn_mfma_f32_16x16x32_bf16(af[i], bl[j], acc[i][j], 0, 0, 0);
                    acc[i][j] = __builtin_amdgcn_mfma_f32_16x16x32_bf16(al[i], bf_[j], acc[i][j], 0, 0, 0);
                }
                if constexpr (DUAL)
                    acc2[i][j] = __builtin_amdgcn_mfma_f32_16x16x32_bf16(af[i], b2f[j], acc2[i][j], 0, 0, 0);
            }
    }
    #pragma unroll
    for (int i = 0; i < 4; ++i) {
        #pragma unroll
        for (int r = 0; r < 4; ++r) {
            const long row = row0 + i * 16 + l4 * 4 + r;
            #pragma unroll
            for (int j = 0; j < 4; ++j) {
                const long col = col0 + j * 16 + l15;
                float v = acc[i][j][r];
                if constexpr (EPI == 0) {
                    int m = (int)row;
                    int bb = m >> 11, tt = m & 2047;
                    outf[((size_t)(tt * NBATCH + bb)) * DIM + col] = v + aux1[col];
                } else if constexpr (EPI == 1) {
                    size_t idx = (size_t)row * N + col;
                    float gg = acc2[i][j][r] + aux2[col];
                    outf[idx] = aux1[idx] + v * (1.f / (1.f + expf(-gg)));
                } else if constexpr (EPI == 2) {
                    size_t idx = (size_t)row * N + col;
                    float u = acc2[i][j][r];
                    outbf[idx] = f2bf((v / (1.f + expf(-v))) * u);
                } else {
                    size_t idx = (size_t)row * N + col;
                    outf[idx] = aux1[idx] + v;
                }
            }
        }
    }
}

// ---------------- liquid recurrence + PLIF, 32 co-resident WGs --------------
// WG wg owns 32 dims [wg*32, wg*32+32). wave g -> dims wg*32+g*4+{0..3};
// lane kp handles k-chunk [kp*16, kp*16+16).
// Exchange: plain stores -> RELEASE/SYSTEM flag (wbl2) -> poll flags ->
// __threadfence_system (inv L1+L2) -> plain dwordx4 loads.
// LDS h layout (PROVEN bijective, 16B aligned): word(b,k) =
//   b*1088 + (k>>6)*68 + (k&63)   [chunk stride 68 > span 64]
__global__ __launch_bounds__(512, 1) void recur_k(
    const float* __restrict__ wrec, const float* __restrict__ U,
    const float* __restrict__ liqtau, const float* __restrict__ plifw,
    float* __restrict__ hg, int* __restrict__ flags, unsigned int* __restrict__ spk) {
    const int tid = threadIdx.x;
    const int wg = blockIdx.x;
    const int g = tid >> 6;
    const int L = tid & 63;
    const int kp = L;
    const int d0 = wg * 32 + g * 4;

    float wreg[4][16];
    #pragma unroll
    for (int d = 0; d < 4; ++d) {
        const float* wr = wrec + (size_t)(d0 + d) * DIM + kp * 16;
        #pragma unroll
        for (int q = 0; q < 4; ++q) {
            f32x4 w4 = *reinterpret_cast<const f32x4*>(wr + q * 4);
            wreg[d][q*4+0] = w4[0]; wreg[d][q*4+1] = w4[1];
            wreg[d][q*4+2] = w4[2]; wreg[d][q*4+3] = w4[3];
        }
    }

    __shared__ float hl[4 * 1088];
    for (int i = tid; i < 4 * 1088; i += 512) hl[i] = 0.f;

    const int od = L >> 2, ob = L & 3;
    const int odim = d0 + od;
    const bool own = (L < 16);
    float hq = 0.f, vq = 0.f, tauv = 1.f;
    unsigned smask = 0u;
    const float decay = 1.f / (1.f + expf(-plifw[0]));
    if (own) {
        float lt = liqtau[odim];
        tauv = (lt > 20.f) ? lt : log1pf(expf(lt));
    }
    const int sel1 = L & 1, sel2 = (L >> 1) & 1, sel4 = (L >> 2) & 1, sel8 = (L >> 3) & 1;

    // lane kp reads k = kp*16 + (0..15): chunk c = kp>>2, in-chunk off = (kp&3)*16
    int cb[4];
    #pragma unroll
    for (int b = 0; b < 4; ++b)
        cb[b] = b * 1088 + (kp >> 2) * 68 + (kp & 3) * 16;
    __syncthreads();

    for (int t = 0; t < TT; ++t) {
        float uvp = 0.f;
        if (own) uvp = U[((size_t)t * NBATCH + ob) * DIM + odim];

        // a[v], v = d*4+b
        float a[16];
        #pragma unroll
        for (int v = 0; v < 16; ++v) a[v] = 0.f;
        #pragma unroll
        for (int q = 0; q < 4; ++q) {
            const f32x4 h0 = *reinterpret_cast<const f32x4*>(hl + cb[0] + q * 4);
            const f32x4 h1 = *reinterpret_cast<const f32x4*>(hl + cb[1] + q * 4);
            const f32x4 h2 = *reinterpret_cast<const f32x4*>(hl + cb[2] + q * 4);
            const f32x4 h3 = *reinterpret_cast<const f32x4*>(hl + cb[3] + q * 4);
            #pragma unroll
            for (int d = 0; d < 4; ++d)
                #pragma unroll
                for (int e = 0; e < 4; ++e) {
                    const float w = wreg[d][q * 4 + e];
                    a[d*4+0] = fmaf(w, h0[e], a[d*4+0]);
                    a[d*4+1] = fmaf(w, h1[e], a[d*4+1]);
                    a[d*4+2] = fmaf(w, h2[e], a[d*4+2]);
                    a[d*4+3] = fmaf(w, h3[e], a[d*4+3]);
                }
        }
        // butterfly-scatter reduce: lane L ends with sum_lanes(a[L&15]) in a[0]
        #pragma unroll
        for (int j = 0; j < 8; ++j) {
            float snd = sel1 ? a[2*j] : a[2*j+1];
            float kept = sel1 ? a[2*j+1] : a[2*j];
            a[j] = kept + __shfl_xor(snd, 1);
        }
        #pragma unroll
        for (int j = 0; j < 4; ++j) {
            float snd = sel2 ? a[2*j] : a[2*j+1];
            float kept = sel2 ? a[2*j+1] : a[2*j];
            a[j] = kept + __shfl_xor(snd, 2);
        }
        #pragma unroll
        for (int j = 0; j < 2; ++j) {
            float snd = sel4 ? a[2*j] : a[2*j+1];
            float kept = sel4 ? a[2*j+1] : a[2*j];
            a[j] = kept + __shfl_xor(snd, 4);
        }
        {
            float snd = sel8 ? a[0] : a[1];
            float kept = sel8 ? a[1] : a[0];
            a[0] = kept + __shfl_xor(snd, 8);
        }
        a[0] += __shfl_xor(a[0], 16);
        a[0] += __shfl_xor(a[0], 32);

        if (own) {
            float pre = a[0] + uvp;
            float th = tanhf(pre);
            float hn = hq + (th - hq) / tauv;
            hq = hn;
            float v = vq + decay * (hn - vq);
            float s = ((v - THRESH) > 0.f) ? 1.f : 0.f;
            vq = v - s * THRESH;
            smask |= (s > 0.f ? 1u : 0u) << (t & 31);
            if ((t & 31) == 31) {
                spk[ob * 65536 + (t >> 5) * 1024 + odim] = smask;
                smask = 0u;
            }
            hg[(size_t)(t & 1) * 4096 + ob * 1024 + odim] = hn;  // plain store
        }
        if (t == TT - 1) break;
        __syncthreads();  // all waves drain vmcnt -> h stores in L2
        if (tid == 0)     // RELEASE/SYSTEM: compiler emits L2 writeback first
            __hip_atomic_store(&flags[wg], t + 1, __ATOMIC_RELEASE, __HIP_MEMORY_SCOPE_SYSTEM);
        if (g == 0) {
            while (__hip_atomic_load(&flags[L & 31], __ATOMIC_RELAXED,
                                     __HIP_MEMORY_SCOPE_SYSTEM) < t + 1) {}
            __threadfence_system();  // inv L1+L2 before plain data loads
        }
        __syncthreads();
        {
            const float* src = hg + (size_t)(t & 1) * 4096;
            const int b = tid >> 7, k0 = (tid & 127) * 8;
            const int w = b * 1088 + (k0 >> 6) * 68 + (k0 & 63);
            f32x4 va = *reinterpret_cast<const f32x4*>(src + b * 1024 + k0);
            f32x4 vb = *reinterpret_cast<const f32x4*>(src + b * 1024 + k0 + 4);
            *reinterpret_cast<f32x4*>(hl + w) = va;
            *reinterpret_cast<f32x4*>(hl + w + 4) = vb;
        }
        __syncthreads();
    }
}

extern "C" void kernel_launch(void* const* d_in, const int* in_sizes, int n_in,
                              void* d_out, int out_size, void* d_ws, size_t ws_size,
                              hipStream_t stream) {
    (void)in_sizes; (void)n_in; (void)out_size; (void)ws_size;
    const float* x     = (const float*)d_in[0];
    const float* ln1   = (const float*)d_in[1];
    const float* win   = (const float*)d_in[2];
    const float* wrec  = (const float*)d_in[3];
    const float* liqb  = (const float*)d_in[4];
    const float* liqtau= (const float*)d_in[5];
    const float* plifw = (const float*)d_in[6];
    const float* synw  = (const float*)d_in[7];
    const float* gatew = (const float*)d_in[8];
    const float* gateb = (const float*)d_in[9];
    const float* ln2   = (const float*)d_in[10];
    const float* wgp   = (const float*)d_in[11];
    const float* wup   = (const float*)d_in[12];
    const float* wdp   = (const float*)d_in[13];
    const void*  mask  = d_in[14];
    float* dout = (float*)d_out;
    char* ws = (char*)d_ws;
    const size_t MB = (size_t)1 << 20;

    unsigned short* winh  = (unsigned short*)(ws + 0 * MB);
    unsigned short* winl  = (unsigned short*)(ws + 2 * MB);
    unsigned short* weffb = (unsigned short*)(ws + 4 * MB);
    unsigned short* gatewb= (unsigned short*)(ws + 6 * MB);
    unsigned short* wgb   = (unsigned short*)(ws + 8 * MB);
    unsigned short* wub   = (unsigned short*)(ws + 24 * MB);
    unsigned short* wdb   = (unsigned short*)(ws + 40 * MB);
    unsigned short* ahi   = (unsigned short*)(ws + 56 * MB);   // reused as y_bf
    unsigned short* alo   = (unsigned short*)(ws + 72 * MB);
    float*          Ubuf  = (float*)(ws + 88 * MB);            // reused as hff chunk
    unsigned short* hffb  = (unsigned short*)(ws + 88 * MB);
    unsigned short* sbf   = (unsigned short*)(ws + 120 * MB);
    float*          x2    = (float*)(ws + 136 * MB);
    float*          hgb   = (float*)(ws + 168 * MB);           // 32 KB
    int*            flags = (int*)(ws + 168 * MB + 64 * 1024); // 128 B
    int*            flag  = (int*)(ws + 168 * MB + 80 * 1024);
    unsigned int*   spk   = (unsigned int*)(ws + 169 * MB);    // 1 MB

    hipMemsetAsync(flags, 0, 512, stream);
    maskprobe_k<<<1, 256, 0, stream>>>((const unsigned int*)mask, flag);
    weff_k<<<1024, 256, 0, stream>>>(synw, mask, flag, weffb);
    split_k<<<1024, 256, 0, stream>>>(win, winh, winl, DIM * DIM);
    conv_k<<<1024, 256, 0, stream>>>(gatew, gatewb, DIM * DIM);
    conv_k<<<2048, 256, 0, stream>>>(wgp, wgb, HFF * DIM);
    conv_k<<<2048, 256, 0, stream>>>(wup, wub, HFF * DIM);
    conv_k<<<2048, 256, 0, stream>>>(wdp, wdb, DIM * HFF);

    rms_k<true><<<NBATCH * TT, 256, 0, stream>>>(x, ln1, ahi, alo);
    gemm_k<0><<<dim3(DIM / 128, (NBATCH * TT) / 128), 256, 0, stream>>>(
        ahi, alo, winh, winl, nullptr, liqb, nullptr, Ubuf, nullptr,
        NBATCH * TT, DIM, DIM);

    recur_k<<<PWG, 512, 0, stream>>>(wrec, Ubuf, liqtau, plifw, hgb, flags, spk);
    spkexp_k<<<(NBATCH * 64 * 1024) / 256, 256, 0, stream>>>(spk, sbf);

    gemm_k<1><<<dim3(DIM / 128, (NBATCH * TT) / 128), 256, 0, stream>>>(
        sbf, nullptr, weffb, nullptr, gatewb, x, gateb, x2, nullptr,
        NBATCH * TT, DIM, DIM);

    rms_k<false><<<NBATCH * TT, 256, 0, stream>>>(x2, ln2, ahi, nullptr);

    const int CH = 2048;  // FFN row-chunk to bound hff scratch to 32 MB
    for (int c = 0; c < (NBATCH * TT) / CH; ++c) {
        const size_t ro = (size_t)c * CH;
        gemm_k<2><<<dim3(HFF / 128, CH / 128), 256, 0, stream>>>(
            ahi + ro * DIM, nullptr, wgb, nullptr, wub, nullptr, nullptr,
            nullptr, hffb, CH, HFF, DIM);
        gemm_k<3><<<dim3(DIM / 128, CH / 128), 256, 0, stream>>>(
            hffb, nullptr, wdb, nullptr, nullptr, x2 + ro * DIM, nullptr,
            dout + ro * DIM, nullptr, CH, DIM, HFF);
    }
}

// Round 6
// 9552.906 us; speedup vs baseline: 2.9392x; 1.2331x over previous
//
#include <hip/hip_runtime.h>
#include <hip/hip_bf16.h>

#define TT 2048
#define DIM 1024
#define HFF 8192
#define NBATCH 4
#define PWG 32
#define THRESH 0.05f

typedef __bf16 bf16x8 __attribute__((ext_vector_type(8)));
typedef float f32x4 __attribute__((ext_vector_type(4)));

__device__ __forceinline__ unsigned short f2bf(float f) {
    __hip_bfloat16 h = __float2bfloat16(f);
    return __builtin_bit_cast(unsigned short, h);
}
__device__ __forceinline__ float bf2f(unsigned short u) {
    return __bfloat162float(__builtin_bit_cast(__hip_bfloat16, u));
}
__device__ __forceinline__ bf16x8 ldf(const unsigned short* p) {
    return *reinterpret_cast<const bf16x8*>(p);
}

// MALL-coherent (cross-XCD) 16B load: bypass L1 (sc0) and L2 (sc1).
__device__ __forceinline__ void ld2x4_mall(const float* p0, const float* p1,
                                           f32x4* a, f32x4* b) {
    asm volatile("global_load_dwordx4 %0, %2, off sc0 sc1\n\t"
                 "global_load_dwordx4 %1, %3, off sc0 sc1\n\t"
                 "s_waitcnt vmcnt(0)"
                 : "=&v"(*a), "=&v"(*b) : "v"(p0), "v"(p1) : "memory");
}

// ---------------- mask dtype probe: 1 = int32 mask, 0 = uint8 mask ----------
__global__ void maskprobe_k(const unsigned int* mask_words, int* flag) {
    __shared__ int allok;
    if (threadIdx.x == 0) allok = 1;
    __syncthreads();
    int ok = 1;
    for (int i = 0; i < 16; ++i) {
        unsigned int w = mask_words[threadIdx.x * 16 + i];
        if (w > 1u) ok = 0;
    }
    if (!ok) atomicAnd(&allok, 0);
    __syncthreads();
    if (threadIdx.x == 0) flag[0] = allok;
}

// ---------------- w_eff = syn_w * mask  -> bf16 ----------------
__global__ void weff_k(const float* __restrict__ synw, const void* __restrict__ mask,
                       const int* __restrict__ flag, unsigned short* __restrict__ dst) {
    const int isInt = flag[0];
    const int n = DIM * DIM;
    for (int i = blockIdx.x * 256 + threadIdx.x; i < n; i += gridDim.x * 256) {
        bool m;
        if (isInt) m = ((const int*)mask)[i] != 0;
        else       m = ((const unsigned char*)mask)[i] != 0;
        dst[i] = f2bf(m ? synw[i] : 0.f);
    }
}

// ---------------- f32 -> bf16 convert ----------------
__global__ void conv_k(const float* __restrict__ src, unsigned short* __restrict__ dst, int n) {
    for (int i = blockIdx.x * 256 + threadIdx.x; i < n; i += gridDim.x * 256)
        dst[i] = f2bf(src[i]);
}

// ---------------- f32 -> bf16 hi/lo split ----------------
__global__ void split_k(const float* __restrict__ src, unsigned short* __restrict__ hi,
                        unsigned short* __restrict__ lo, int n) {
    for (int i = blockIdx.x * 256 + threadIdx.x; i < n; i += gridDim.x * 256) {
        float v = src[i];
        unsigned short h = f2bf(v);
        hi[i] = h;
        lo[i] = f2bf(v - bf2f(h));
    }
}

// ---------------- spike bit expansion: u32 bits -> bf16 {0,1} ----------------
__global__ void spkexp_k(const unsigned int* __restrict__ spk, unsigned short* __restrict__ sbf) {
    const int i = blockIdx.x * 256 + threadIdx.x;   // 4*64*1024 words
    const unsigned int w = spk[i];
    const int d = i & 1023, t32 = (i >> 10) & 63, b = i >> 16;
    const size_t base = ((size_t)b * TT + (size_t)t32 * 32) * DIM + d;
    #pragma unroll
    for (int j = 0; j < 32; ++j)
        sbf[base + (size_t)j * DIM] = ((w >> j) & 1u) ? (unsigned short)0x3F80 : (unsigned short)0;
}

// ---------------- rmsnorm; SPLIT: also emit lo residual ----------------
template <bool SPLIT>
__global__ void rms_k(const float* __restrict__ xin, const float* __restrict__ w,
                      unsigned short* __restrict__ hi, unsigned short* __restrict__ lo) {
    const int row = blockIdx.x;
    const int tid = threadIdx.x;
    const float4 xv = *reinterpret_cast<const float4*>(xin + (size_t)row * DIM + tid * 4);
    float ss = xv.x * xv.x + xv.y * xv.y + xv.z * xv.z + xv.w * xv.w;
    #pragma unroll
    for (int m = 1; m <= 32; m <<= 1) ss += __shfl_xor(ss, m);
    __shared__ float red[5];
    if ((tid & 63) == 0) red[tid >> 6] = ss;
    __syncthreads();
    if (tid == 0) {
        float s = red[0] + red[1] + red[2] + red[3];
        red[4] = 1.f / sqrtf(s * (1.f / DIM) + 1e-6f);
    }
    __syncthreads();
    const float scale = red[4];
    const float wv[4] = {w[tid*4], w[tid*4+1], w[tid*4+2], w[tid*4+3]};
    const float xa[4] = {xv.x, xv.y, xv.z, xv.w};
    #pragma unroll
    for (int i = 0; i < 4; ++i) {
        float v = xa[i] * scale * wv[i];
        unsigned short h = f2bf(v);
        hi[(size_t)row * DIM + tid * 4 + i] = h;
        if constexpr (SPLIT) lo[(size_t)row * DIM + tid * 4 + i] = f2bf(v - bf2f(h));
    }
}

// ---------------- generic MFMA GEMM: C = A @ B^T ----------------
template <int EPI>
__global__ __launch_bounds__(256, 1) void gemm_k(
    const unsigned short* __restrict__ A,  const unsigned short* __restrict__ Alo,
    const unsigned short* __restrict__ B1, const unsigned short* __restrict__ B1lo,
    const unsigned short* __restrict__ B2,
    const float* __restrict__ aux1, const float* __restrict__ aux2,
    float* __restrict__ outf, unsigned short* __restrict__ outbf,
    int M, int N, int K) {
    constexpr bool HILO = (EPI == 0);
    constexpr bool DUAL = (EPI == 1 || EPI == 2);
    const int lane = threadIdx.x & 63;
    const int wv = threadIdx.x >> 6;
    const int l15 = lane & 15, l4 = lane >> 4;
    const long row0 = (long)blockIdx.y * 128 + (wv >> 1) * 64;
    const long col0 = (long)blockIdx.x * 128 + (wv & 1) * 64;
    long aoff[4], boff[4];
    #pragma unroll
    for (int i = 0; i < 4; ++i) {
        aoff[i] = (row0 + i * 16 + l15) * (long)K + l4 * 8;
        boff[i] = (col0 + i * 16 + l15) * (long)K + l4 * 8;
    }
    f32x4 acc[4][4];
    f32x4 acc2[DUAL ? 4 : 1][DUAL ? 4 : 1];
    #pragma unroll
    for (int i = 0; i < 4; ++i)
        #pragma unroll
        for (int j = 0; j < 4; ++j) {
            acc[i][j] = (f32x4){0.f, 0.f, 0.f, 0.f};
            if constexpr (DUAL) acc2[i][j] = (f32x4){0.f, 0.f, 0.f, 0.f};
        }
    for (int kk = 0; kk < K; kk += 32) {
        bf16x8 af[4], bf_[4], al[4], bl[4], b2f[4];
        #pragma unroll
        for (int i = 0; i < 4; ++i) {
            af[i] = ldf(A + aoff[i] + kk);
            bf_[i] = ldf(B1 + boff[i] + kk);
            if constexpr (HILO) {
                al[i] = ldf(Alo + aoff[i] + kk);
                bl[i] = ldf(B1lo + boff[i] + kk);
            }
            if constexpr (DUAL) b2f[i] = ldf(B2 + boff[i] + kk);
        }
        #pragma unroll
        for (int i = 0; i < 4; ++i)
            #pragma unroll
            for (int j = 0; j < 4; ++j) {
                acc[i][j] = __builtin_amdgcn_mfma_f32_16x16x32_bf16(af[i], bf_[j], acc[i][j], 0, 0, 0);
                if constexpr (HILO) {
                    acc[i][j] = __builtin_amdgcn_mfma_f32_16x16x32_bf16(af[i], bl[j], acc[i][j], 0, 0, 0);
                    acc[i][j] = __builtin_amdgcn_mfma_f32_16x16x32_bf16(al[i], bf_[j], acc[i][j], 0, 0, 0);
                }
                if constexpr (DUAL)
                    acc2[i][j] = __builtin_amdgcn_mfma_f32_16x16x32_bf16(af[i], b2f[j], acc2[i][j], 0, 0, 0);
            }
    }
    #pragma unroll
    for (int i = 0; i < 4; ++i) {
        #pragma unroll
        for (int r = 0; r < 4; ++r) {
            const long row = row0 + i * 16 + l4 * 4 + r;
            #pragma unroll
            for (int j = 0; j < 4; ++j) {
                const long col = col0 + j * 16 + l15;
                float v = acc[i][j][r];
                if constexpr (EPI == 0) {
                    int m = (int)row;
                    int bb = m >> 11, tt = m & 2047;
                    outf[((size_t)(tt * NBATCH + bb)) * DIM + col] = v + aux1[col];
                } else if constexpr (EPI == 1) {
                    size_t idx = (size_t)row * N + col;
                    float gg = acc2[i][j][r] + aux2[col];
                    outf[idx] = aux1[idx] + v * (1.f / (1.f + expf(-gg)));
                } else if constexpr (EPI == 2) {
                    size_t idx = (size_t)row * N + col;
                    float u = acc2[i][j][r];
                    outbf[idx] = f2bf((v / (1.f + expf(-v))) * u);
                } else {
                    size_t idx = (size_t)row * N + col;
                    outf[idx] = aux1[idx] + v;
                }
            }
        }
    }
}

// ---------------- liquid recurrence + PLIF, 32 co-resident WGs --------------
// WG wg owns 32 dims [wg*32, wg*32+32). wave g -> dims wg*32+g*4+{0..3};
// lane kp handles k-chunk [kp*16, kp*16+16).
// Exchange (targeted MALL coherence, no cache-wide flush/inv):
//   h stores  : RELAXED/SYSTEM scalar (sc0 sc1 write-through to MALL)
//   flag      : RELEASE/SYSTEM after __syncthreads (L2 clean -> cheap wbl2)
//   poll      : RELAXED/SYSTEM; then dwordx4 sc0 sc1 reads (no threadfence)
// LDS h layout (bijective, 16B aligned): word(b,k) = b*1088 + (k>>6)*68 + (k&63)
__global__ __launch_bounds__(512, 1) void recur_k(
    const float* __restrict__ wrec, const float* __restrict__ U,
    const float* __restrict__ liqtau, const float* __restrict__ plifw,
    float* __restrict__ hg, int* __restrict__ flags, unsigned int* __restrict__ spk) {
    const int tid = threadIdx.x;
    const int wg = blockIdx.x;
    const int g = tid >> 6;
    const int L = tid & 63;
    const int kp = L;
    const int d0 = wg * 32 + g * 4;

    float wreg[4][16];
    #pragma unroll
    for (int d = 0; d < 4; ++d) {
        const float* wr = wrec + (size_t)(d0 + d) * DIM + kp * 16;
        #pragma unroll
        for (int q = 0; q < 4; ++q) {
            f32x4 w4 = *reinterpret_cast<const f32x4*>(wr + q * 4);
            wreg[d][q*4+0] = w4[0]; wreg[d][q*4+1] = w4[1];
            wreg[d][q*4+2] = w4[2]; wreg[d][q*4+3] = w4[3];
        }
    }

    __shared__ float hl[4 * 1088];
    for (int i = tid; i < 4 * 1088; i += 512) hl[i] = 0.f;

    const int od = L >> 2, ob = L & 3;
    const int odim = d0 + od;
    const bool own = (L < 16);
    float hq = 0.f, vq = 0.f, tauv = 1.f;
    unsigned smask = 0u;
    const float decay = 1.f / (1.f + expf(-plifw[0]));
    if (own) {
        float lt = liqtau[odim];
        tauv = (lt > 20.f) ? lt : log1pf(expf(lt));
    }
    const int sel1 = L & 1, sel2 = (L >> 1) & 1, sel4 = (L >> 2) & 1, sel8 = (L >> 3) & 1;

    int cb[4];
    #pragma unroll
    for (int b = 0; b < 4; ++b)
        cb[b] = b * 1088 + (kp >> 2) * 68 + (kp & 3) * 16;
    __syncthreads();

    for (int t = 0; t < TT; ++t) {
        float uvp = 0.f;
        if (own) uvp = U[((size_t)t * NBATCH + ob) * DIM + odim];

        float a[16];
        #pragma unroll
        for (int v = 0; v < 16; ++v) a[v] = 0.f;
        #pragma unroll
        for (int q = 0; q < 4; ++q) {
            const f32x4 h0 = *reinterpret_cast<const f32x4*>(hl + cb[0] + q * 4);
            const f32x4 h1 = *reinterpret_cast<const f32x4*>(hl + cb[1] + q * 4);
            const f32x4 h2 = *reinterpret_cast<const f32x4*>(hl + cb[2] + q * 4);
            const f32x4 h3 = *reinterpret_cast<const f32x4*>(hl + cb[3] + q * 4);
            #pragma unroll
            for (int d = 0; d < 4; ++d)
                #pragma unroll
                for (int e = 0; e < 4; ++e) {
                    const float w = wreg[d][q * 4 + e];
                    a[d*4+0] = fmaf(w, h0[e], a[d*4+0]);
                    a[d*4+1] = fmaf(w, h1[e], a[d*4+1]);
                    a[d*4+2] = fmaf(w, h2[e], a[d*4+2]);
                    a[d*4+3] = fmaf(w, h3[e], a[d*4+3]);
                }
        }
        // butterfly-scatter reduce: lane L ends with sum_lanes(a[L&15]) in a[0]
        #pragma unroll
        for (int j = 0; j < 8; ++j) {
            float snd = sel1 ? a[2*j] : a[2*j+1];
            float kept = sel1 ? a[2*j+1] : a[2*j];
            a[j] = kept + __shfl_xor(snd, 1);
        }
        #pragma unroll
        for (int j = 0; j < 4; ++j) {
            float snd = sel2 ? a[2*j] : a[2*j+1];
            float kept = sel2 ? a[2*j+1] : a[2*j];
            a[j] = kept + __shfl_xor(snd, 2);
        }
        #pragma unroll
        for (int j = 0; j < 2; ++j) {
            float snd = sel4 ? a[2*j] : a[2*j+1];
            float kept = sel4 ? a[2*j+1] : a[2*j];
            a[j] = kept + __shfl_xor(snd, 4);
        }
        {
            float snd = sel8 ? a[0] : a[1];
            float kept = sel8 ? a[1] : a[0];
            a[0] = kept + __shfl_xor(snd, 8);
        }
        a[0] += __shfl_xor(a[0], 16);
        a[0] += __shfl_xor(a[0], 32);

        if (own) {
            float pre = a[0] + uvp;
            float th = tanhf(pre);
            float hn = hq + (th - hq) / tauv;
            hq = hn;
            float v = vq + decay * (hn - vq);
            float s = ((v - THRESH) > 0.f) ? 1.f : 0.f;
            vq = v - s * THRESH;
            smask |= (s > 0.f ? 1u : 0u) << (t & 31);
            if ((t & 31) == 31) {
                __hip_atomic_store(&spk[ob * 65536 + (t >> 5) * 1024 + odim], smask,
                                   __ATOMIC_RELAXED, __HIP_MEMORY_SCOPE_SYSTEM);
                smask = 0u;
            }
            // write-through to MALL (sc0 sc1); acked before barrier releases
            __hip_atomic_store(&hg[(size_t)(t & 1) * 4096 + ob * 1024 + odim], hn,
                               __ATOMIC_RELAXED, __HIP_MEMORY_SCOPE_SYSTEM);
        }
        if (t == TT - 1) break;
        __syncthreads();  // per-wave vmcnt(0): all write-through h stores at MALL
        if (tid == 0)     // release on clean L2 -> cheap; publishes step t
            __hip_atomic_store(&flags[wg], t + 1, __ATOMIC_RELEASE, __HIP_MEMORY_SCOPE_SYSTEM);
        if (g == 0) {
            while (__hip_atomic_load(&flags[L & 31], __ATOMIC_RELAXED,
                                     __HIP_MEMORY_SCOPE_SYSTEM) < t + 1) {}
        }
        __syncthreads();
        {
            const float* src = hg + (size_t)(t & 1) * 4096;
            const int b = tid >> 7, k0 = (tid & 127) * 8;
            const int w = b * 1088 + (k0 >> 6) * 68 + (k0 & 63);
            f32x4 va, vb;
            ld2x4_mall(src + b * 1024 + k0, src + b * 1024 + k0 + 4, &va, &vb);
            *reinterpret_cast<f32x4*>(hl + w) = va;
            *reinterpret_cast<f32x4*>(hl + w + 4) = vb;
        }
        __syncthreads();
    }
}

extern "C" void kernel_launch(void* const* d_in, const int* in_sizes, int n_in,
                              void* d_out, int out_size, void* d_ws, size_t ws_size,
                              hipStream_t stream) {
    (void)in_sizes; (void)n_in; (void)out_size; (void)ws_size;
    const float* x     = (const float*)d_in[0];
    const float* ln1   = (const float*)d_in[1];
    const float* win   = (const float*)d_in[2];
    const float* wrec  = (const float*)d_in[3];
    const float* liqb  = (const float*)d_in[4];
    const float* liqtau= (const float*)d_in[5];
    const float* plifw = (const float*)d_in[6];
    const float* synw  = (const float*)d_in[7];
    const float* gatew = (const float*)d_in[8];
    const float* gateb = (const float*)d_in[9];
    const float* ln2   = (const float*)d_in[10];
    const float* wgp   = (const float*)d_in[11];
    const float* wup   = (const float*)d_in[12];
    const float* wdp   = (const float*)d_in[13];
    const void*  mask  = d_in[14];
    float* dout = (float*)d_out;
    char* ws = (char*)d_ws;
    const size_t MB = (size_t)1 << 20;

    unsigned short* winh  = (unsigned short*)(ws + 0 * MB);
    unsigned short* winl  = (unsigned short*)(ws + 2 * MB);
    unsigned short* weffb = (unsigned short*)(ws + 4 * MB);
    unsigned short* gatewb= (unsigned short*)(ws + 6 * MB);
    unsigned short* wgb   = (unsigned short*)(ws + 8 * MB);
    unsigned short* wub   = (unsigned short*)(ws + 24 * MB);
    unsigned short* wdb   = (unsigned short*)(ws + 40 * MB);
    unsigned short* ahi   = (unsigned short*)(ws + 56 * MB);   // reused as y_bf
    unsigned short* alo   = (unsigned short*)(ws + 72 * MB);
    float*          Ubuf  = (float*)(ws + 88 * MB);            // reused as hff chunk
    unsigned short* hffb  = (unsigned short*)(ws + 88 * MB);
    unsigned short* sbf   = (unsigned short*)(ws + 120 * MB);
    float*          x2    = (float*)(ws + 136 * MB);
    float*          hgb   = (float*)(ws + 168 * MB);           // 32 KB
    int*            flags = (int*)(ws + 168 * MB + 64 * 1024); // 128 B
    int*            flag  = (int*)(ws + 168 * MB + 80 * 1024);
    unsigned int*   spk   = (unsigned int*)(ws + 169 * MB);    // 1 MB

    hipMemsetAsync(flags, 0, 512, stream);
    maskprobe_k<<<1, 256, 0, stream>>>((const unsigned int*)mask, flag);
    weff_k<<<1024, 256, 0, stream>>>(synw, mask, flag, weffb);
    split_k<<<1024, 256, 0, stream>>>(win, winh, winl, DIM * DIM);
    conv_k<<<1024, 256, 0, stream>>>(gatew, gatewb, DIM * DIM);
    conv_k<<<2048, 256, 0, stream>>>(wgp, wgb, HFF * DIM);
    conv_k<<<2048, 256, 0, stream>>>(wup, wub, HFF * DIM);
    conv_k<<<2048, 256, 0, stream>>>(wdp, wdb, DIM * HFF);

    rms_k<true><<<NBATCH * TT, 256, 0, stream>>>(x, ln1, ahi, alo);
    gemm_k<0><<<dim3(DIM / 128, (NBATCH * TT) / 128), 256, 0, stream>>>(
        ahi, alo, winh, winl, nullptr, liqb, nullptr, Ubuf, nullptr,
        NBATCH * TT, DIM, DIM);

    recur_k<<<PWG, 512, 0, stream>>>(wrec, Ubuf, liqtau, plifw, hgb, flags, spk);
    spkexp_k<<<(NBATCH * 64 * 1024) / 256, 256, 0, stream>>>(spk, sbf);

    gemm_k<1><<<dim3(DIM / 128, (NBATCH * TT) / 128), 256, 0, stream>>>(
        sbf, nullptr, weffb, nullptr, gatewb, x, gateb, x2, nullptr,
        NBATCH * TT, DIM, DIM);

    rms_k<false><<<NBATCH * TT, 256, 0, stream>>>(x2, ln2, ahi, nullptr);

    const int CH = 2048;  // FFN row-chunk to bound hff scratch to 32 MB
    for (int c = 0; c < (NBATCH * TT) / CH; ++c) {
        const size_t ro = (size_t)c * CH;
        gemm_k<2><<<dim3(HFF / 128, CH / 128), 256, 0, stream>>>(
            ahi + ro * DIM, nullptr, wgb, nullptr, wub, nullptr, nullptr,
            nullptr, hffb, CH, HFF, DIM);
        gemm_k<3><<<dim3(DIM / 128, CH / 128), 256, 0, stream>>>(
            hffb, nullptr, wdb, nullptr, nullptr, x2 + ro * DIM, nullptr,
            dout + ro * DIM, nullptr, CH, DIM, HFF);
    }
}

// Round 9
// 8515.581 us; speedup vs baseline: 3.2973x; 1.1218x over previous
//
#include <hip/hip_runtime.h>
#include <hip/hip_bf16.h>

#define TT 2048
#define DIM 1024
#define HFF 8192
#define NBATCH 4
#define PWG 32
#define THRESH 0.05f

typedef __bf16 bf16x8 __attribute__((ext_vector_type(8)));
typedef float f32x4 __attribute__((ext_vector_type(4)));

__device__ __forceinline__ unsigned short f2bf(float f) {
    __hip_bfloat16 h = __float2bfloat16(f);
    return __builtin_bit_cast(unsigned short, h);
}
__device__ __forceinline__ float bf2f(unsigned short u) {
    return __bfloat162float(__builtin_bit_cast(__hip_bfloat16, u));
}
__device__ __forceinline__ bf16x8 ldf(const unsigned short* p) {
    return *reinterpret_cast<const bf16x8*>(p);
}

// MALL-coherent (cross-XCD) 16B load: bypass L1 (sc0) and L2 (sc1).
__device__ __forceinline__ void ld2x4_mall(const float* p0, const float* p1,
                                           f32x4* a, f32x4* b) {
    asm volatile("global_load_dwordx4 %0, %2, off sc0 sc1\n\t"
                 "global_load_dwordx4 %1, %3, off sc0 sc1\n\t"
                 "s_waitcnt vmcnt(0)"
                 : "=&v"(*a), "=&v"(*b) : "v"(p0), "v"(p1) : "memory");
}

// ---------------- mask dtype probe: 1 = int32 mask, 0 = uint8 mask ----------
__global__ void maskprobe_k(const unsigned int* mask_words, int* flag) {
    __shared__ int allok;
    if (threadIdx.x == 0) allok = 1;
    __syncthreads();
    int ok = 1;
    for (int i = 0; i < 16; ++i) {
        unsigned int w = mask_words[threadIdx.x * 16 + i];
        if (w > 1u) ok = 0;
    }
    if (!ok) atomicAnd(&allok, 0);
    __syncthreads();
    if (threadIdx.x == 0) flag[0] = allok;
}

// ---------------- w_eff = syn_w * mask  -> bf16 ----------------
__global__ void weff_k(const float* __restrict__ synw, const void* __restrict__ mask,
                       const int* __restrict__ flag, unsigned short* __restrict__ dst) {
    const int isInt = flag[0];
    const int n = DIM * DIM;
    for (int i = blockIdx.x * 256 + threadIdx.x; i < n; i += gridDim.x * 256) {
        bool m;
        if (isInt) m = ((const int*)mask)[i] != 0;
        else       m = ((const unsigned char*)mask)[i] != 0;
        dst[i] = f2bf(m ? synw[i] : 0.f);
    }
}

// ---------------- f32 -> bf16 convert ----------------
__global__ void conv_k(const float* __restrict__ src, unsigned short* __restrict__ dst, int n) {
    for (int i = blockIdx.x * 256 + threadIdx.x; i < n; i += gridDim.x * 256)
        dst[i] = f2bf(src[i]);
}

// ---------------- f32 -> bf16 hi/lo split ----------------
__global__ void split_k(const float* __restrict__ src, unsigned short* __restrict__ hi,
                        unsigned short* __restrict__ lo, int n) {
    for (int i = blockIdx.x * 256 + threadIdx.x; i < n; i += gridDim.x * 256) {
        float v = src[i];
        unsigned short h = f2bf(v);
        hi[i] = h;
        lo[i] = f2bf(v - bf2f(h));
    }
}

// ---------------- spike bit expansion: u32 bits -> bf16 {0,1} ----------------
__global__ void spkexp_k(const unsigned int* __restrict__ spk, unsigned short* __restrict__ sbf) {
    const int i = blockIdx.x * 256 + threadIdx.x;   // 4*64*1024 words
    const unsigned int w = spk[i];
    const int d = i & 1023, t32 = (i >> 10) & 63, b = i >> 16;
    const size_t base = ((size_t)b * TT + (size_t)t32 * 32) * DIM + d;
    #pragma unroll
    for (int j = 0; j < 32; ++j)
        sbf[base + (size_t)j * DIM] = ((w >> j) & 1u) ? (unsigned short)0x3F80 : (unsigned short)0;
}

// ---------------- rmsnorm; SPLIT: also emit lo residual ----------------
template <bool SPLIT>
__global__ void rms_k(const float* __restrict__ xin, const float* __restrict__ w,
                      unsigned short* __restrict__ hi, unsigned short* __restrict__ lo) {
    const int row = blockIdx.x;
    const int tid = threadIdx.x;
    const float4 xv = *reinterpret_cast<const float4*>(xin + (size_t)row * DIM + tid * 4);
    float ss = xv.x * xv.x + xv.y * xv.y + xv.z * xv.z + xv.w * xv.w;
    #pragma unroll
    for (int m = 1; m <= 32; m <<= 1) ss += __shfl_xor(ss, m);
    __shared__ float red[5];
    if ((tid & 63) == 0) red[tid >> 6] = ss;
    __syncthreads();
    if (tid == 0) {
        float s = red[0] + red[1] + red[2] + red[3];
        red[4] = 1.f / sqrtf(s * (1.f / DIM) + 1e-6f);
    }
    __syncthreads();
    const float scale = red[4];
    const float wv[4] = {w[tid*4], w[tid*4+1], w[tid*4+2], w[tid*4+3]};
    const float xa[4] = {xv.x, xv.y, xv.z, xv.w};
    #pragma unroll
    for (int i = 0; i < 4; ++i) {
        float v = xa[i] * scale * wv[i];
        unsigned short h = f2bf(v);
        hi[(size_t)row * DIM + tid * 4 + i] = h;
        if constexpr (SPLIT) lo[(size_t)row * DIM + tid * 4 + i] = f2bf(v - bf2f(h));
    }
}

// ---------------- generic MFMA GEMM: C = A @ B^T ----------------
template <int EPI>
__global__ __launch_bounds__(256, 1) void gemm_k(
    const unsigned short* __restrict__ A,  const unsigned short* __restrict__ Alo,
    const unsigned short* __restrict__ B1, const unsigned short* __restrict__ B1lo,
    const unsigned short* __restrict__ B2,
    const float* __restrict__ aux1, const float* __restrict__ aux2,
    float* __restrict__ outf, unsigned short* __restrict__ outbf,
    int M, int N, int K) {
    constexpr bool HILO = (EPI == 0);
    constexpr bool DUAL = (EPI == 1 || EPI == 2);
    const int lane = threadIdx.x & 63;
    const int wv = threadIdx.x >> 6;
    const int l15 = lane & 15, l4 = lane >> 4;
    const long row0 = (long)blockIdx.y * 128 + (wv >> 1) * 64;
    const long col0 = (long)blockIdx.x * 128 + (wv & 1) * 64;
    long aoff[4], boff[4];
    #pragma unroll
    for (int i = 0; i < 4; ++i) {
        aoff[i] = (row0 + i * 16 + l15) * (long)K + l4 * 8;
        boff[i] = (col0 + i * 16 + l15) * (long)K + l4 * 8;
    }
    f32x4 acc[4][4];
    f32x4 acc2[DUAL ? 4 : 1][DUAL ? 4 : 1];
    #pragma unroll
    for (int i = 0; i < 4; ++i)
        #pragma unroll
        for (int j = 0; j < 4; ++j) {
            acc[i][j] = (f32x4){0.f, 0.f, 0.f, 0.f};
            if constexpr (DUAL) acc2[i][j] = (f32x4){0.f, 0.f, 0.f, 0.f};
        }
    for (int kk = 0; kk < K; kk += 32) {
        bf16x8 af[4], bf_[4], al[4], bl[4], b2f[4];
        #pragma unroll
        for (int i = 0; i < 4; ++i) {
            af[i] = ldf(A + aoff[i] + kk);
            bf_[i] = ldf(B1 + boff[i] + kk);
            if constexpr (HILO) {
                al[i] = ldf(Alo + aoff[i] + kk);
                bl[i] = ldf(B1lo + boff[i] + kk);
            }
            if constexpr (DUAL) b2f[i] = ldf(B2 + boff[i] + kk);
        }
        #pragma unroll
        for (int i = 0; i < 4; ++i)
            #pragma unroll
            for (int j = 0; j < 4; ++j) {
                acc[i][j] = __builtin_amdgcn_mfma_f32_16x16x32_bf16(af[i], bf_[j], acc[i][j], 0, 0, 0);
                if constexpr (HILO) {
                    acc[i][j] = __builtin_amdgcn_mfma_f32_16x16x32_bf16(af[i], bl[j], acc[i][j], 0, 0, 0);
                    acc[i][j] = __builtin_amdgcn_mfma_f32_16x16x32_bf16(al[i], bf_[j], acc[i][j], 0, 0, 0);
                }
                if constexpr (DUAL)
                    acc2[i][j] = __builtin_amdgcn_mfma_f32_16x16x32_bf16(af[i], b2f[j], acc2[i][j], 0, 0, 0);
            }
    }
    #pragma unroll
    for (int i = 0; i < 4; ++i) {
        #pragma unroll
        for (int r = 0; r < 4; ++r) {
            const long row = row0 + i * 16 + l4 * 4 + r;
            #pragma unroll
            for (int j = 0; j < 4; ++j) {
                const long col = col0 + j * 16 + l15;
                float v = acc[i][j][r];
                if constexpr (EPI == 0) {
                    int m = (int)row;
                    int bb = m >> 11, tt = m & 2047;
                    outf[((size_t)(tt * NBATCH + bb)) * DIM + col] = v + aux1[col];
                } else if constexpr (EPI == 1) {
                    size_t idx = (size_t)row * N + col;
                    float gg = acc2[i][j][r] + aux2[col];
                    outf[idx] = aux1[idx] + v * (1.f / (1.f + expf(-gg)));
                } else if constexpr (EPI == 2) {
                    size_t idx = (size_t)row * N + col;
                    float u = acc2[i][j][r];
                    outbf[idx] = f2bf((v / (1.f + expf(-v))) * u);
                } else {
                    size_t idx = (size_t)row * N + col;
                    outf[idx] = aux1[idx] + v;
                }
            }
        }
    }
}

// ---------------- liquid recurrence + PLIF, 32 co-resident WGs --------------
// EXACT R6 protocol (proven passing) with one change: the per-step flag store
// is RELAXED instead of RELEASE. Justification: h stores are write-through
// (sc0 sc1, never L2-dirty) and COMPLETED (vmcnt drained) at the preceding
// __syncthreads; a later-issued flag store cannot pass already-completed
// stores, and wbl2 had nothing dirty to write back. Removes a full L2
// writeback walk per step.
// LDS h layout (bijective, 16B aligned): word(b,k) = b*1088 + (k>>6)*68 + (k&63)
__global__ __launch_bounds__(512, 1) void recur_k(
    const float* __restrict__ wrec, const float* __restrict__ U,
    const float* __restrict__ liqtau, const float* __restrict__ plifw,
    float* __restrict__ hg, int* __restrict__ flags, unsigned int* __restrict__ spk) {
    const int tid = threadIdx.x;
    const int wg = blockIdx.x;
    const int g = tid >> 6;
    const int L = tid & 63;
    const int kp = L;
    const int d0 = wg * 32 + g * 4;

    float wreg[4][16];
    #pragma unroll
    for (int d = 0; d < 4; ++d) {
        const float* wr = wrec + (size_t)(d0 + d) * DIM + kp * 16;
        #pragma unroll
        for (int q = 0; q < 4; ++q) {
            f32x4 w4 = *reinterpret_cast<const f32x4*>(wr + q * 4);
            wreg[d][q*4+0] = w4[0]; wreg[d][q*4+1] = w4[1];
            wreg[d][q*4+2] = w4[2]; wreg[d][q*4+3] = w4[3];
        }
    }

    __shared__ float hl[4 * 1088];
    for (int i = tid; i < 4 * 1088; i += 512) hl[i] = 0.f;

    const int od = L >> 2, ob = L & 3;
    const int odim = d0 + od;
    const bool own = (L < 16);
    float hq = 0.f, vq = 0.f, tauv = 1.f;
    unsigned smask = 0u;
    const float decay = 1.f / (1.f + expf(-plifw[0]));
    if (own) {
        float lt = liqtau[odim];
        tauv = (lt > 20.f) ? lt : log1pf(expf(lt));
    }
    const int sel1 = L & 1, sel2 = (L >> 1) & 1, sel4 = (L >> 2) & 1, sel8 = (L >> 3) & 1;

    int cb[4];
    #pragma unroll
    for (int b = 0; b < 4; ++b)
        cb[b] = b * 1088 + (kp >> 2) * 68 + (kp & 3) * 16;
    __syncthreads();

    for (int t = 0; t < TT; ++t) {
        float uvp = 0.f;
        if (own) uvp = U[((size_t)t * NBATCH + ob) * DIM + odim];

        float a[16];
        #pragma unroll
        for (int v = 0; v < 16; ++v) a[v] = 0.f;
        #pragma unroll
        for (int q = 0; q < 4; ++q) {
            const f32x4 h0 = *reinterpret_cast<const f32x4*>(hl + cb[0] + q * 4);
            const f32x4 h1 = *reinterpret_cast<const f32x4*>(hl + cb[1] + q * 4);
            const f32x4 h2 = *reinterpret_cast<const f32x4*>(hl + cb[2] + q * 4);
            const f32x4 h3 = *reinterpret_cast<const f32x4*>(hl + cb[3] + q * 4);
            #pragma unroll
            for (int d = 0; d < 4; ++d)
                #pragma unroll
                for (int e = 0; e < 4; ++e) {
                    const float w = wreg[d][q * 4 + e];
                    a[d*4+0] = fmaf(w, h0[e], a[d*4+0]);
                    a[d*4+1] = fmaf(w, h1[e], a[d*4+1]);
                    a[d*4+2] = fmaf(w, h2[e], a[d*4+2]);
                    a[d*4+3] = fmaf(w, h3[e], a[d*4+3]);
                }
        }
        // butterfly-scatter reduce: lane L ends with sum_lanes(a[L&15]) in a[0]
        #pragma unroll
        for (int j = 0; j < 8; ++j) {
            float snd = sel1 ? a[2*j] : a[2*j+1];
            float kept = sel1 ? a[2*j+1] : a[2*j];
            a[j] = kept + __shfl_xor(snd, 1);
        }
        #pragma unroll
        for (int j = 0; j < 4; ++j) {
            float snd = sel2 ? a[2*j] : a[2*j+1];
            float kept = sel2 ? a[2*j+1] : a[2*j];
            a[j] = kept + __shfl_xor(snd, 2);
        }
        #pragma unroll
        for (int j = 0; j < 2; ++j) {
            float snd = sel4 ? a[2*j] : a[2*j+1];
            float kept = sel4 ? a[2*j+1] : a[2*j];
            a[j] = kept + __shfl_xor(snd, 4);
        }
        {
            float snd = sel8 ? a[0] : a[1];
            float kept = sel8 ? a[1] : a[0];
            a[0] = kept + __shfl_xor(snd, 8);
        }
        a[0] += __shfl_xor(a[0], 16);
        a[0] += __shfl_xor(a[0], 32);

        if (own) {
            float pre = a[0] + uvp;
            float th = tanhf(pre);
            float hn = hq + (th - hq) / tauv;
            hq = hn;
            float v = vq + decay * (hn - vq);
            float s = ((v - THRESH) > 0.f) ? 1.f : 0.f;
            vq = v - s * THRESH;
            smask |= (s > 0.f ? 1u : 0u) << (t & 31);
            if ((t & 31) == 31) {
                __hip_atomic_store(&spk[ob * 65536 + (t >> 5) * 1024 + odim], smask,
                                   __ATOMIC_RELAXED, __HIP_MEMORY_SCOPE_SYSTEM);
                smask = 0u;
            }
            // write-through to MALL (sc0 sc1); acked before barrier releases
            __hip_atomic_store(&hg[(size_t)(t & 1) * 4096 + ob * 1024 + odim], hn,
                               __ATOMIC_RELAXED, __HIP_MEMORY_SCOPE_SYSTEM);
        }
        if (t == TT - 1) break;
        __syncthreads();  // per-wave vmcnt(0): all write-through h stores at MALL
        if (tid == 0)     // RELAXED: h stores already completed; no wbl2 walk
            __hip_atomic_store(&flags[wg], t + 1, __ATOMIC_RELAXED, __HIP_MEMORY_SCOPE_SYSTEM);
        if (g == 0) {
            while (__hip_atomic_load(&flags[L & 31], __ATOMIC_RELAXED,
                                     __HIP_MEMORY_SCOPE_SYSTEM) < t + 1) {}
        }
        __syncthreads();
        {
            const float* src = hg + (size_t)(t & 1) * 4096;
            const int b = tid >> 7, k0 = (tid & 127) * 8;
            const int w = b * 1088 + (k0 >> 6) * 68 + (k0 & 63);
            f32x4 va, vb;
            ld2x4_mall(src + b * 1024 + k0, src + b * 1024 + k0 + 4, &va, &vb);
            *reinterpret_cast<f32x4*>(hl + w) = va;
            *reinterpret_cast<f32x4*>(hl + w + 4) = vb;
        }
        __syncthreads();
    }
}

extern "C" void kernel_launch(void* const* d_in, const int* in_sizes, int n_in,
                              void* d_out, int out_size, void* d_ws, size_t ws_size,
                              hipStream_t stream) {
    (void)in_sizes; (void)n_in; (void)out_size; (void)ws_size;
    const float* x     = (const float*)d_in[0];
    const float* ln1   = (const float*)d_in[1];
    const float* win   = (const float*)d_in[2];
    const float* wrec  = (const float*)d_in[3];
    const float* liqb  = (const float*)d_in[4];
    const float* liqtau= (const float*)d_in[5];
    const float* plifw = (const float*)d_in[6];
    const float* synw  = (const float*)d_in[7];
    const float* gatew = (const float*)d_in[8];
    const float* gateb = (const float*)d_in[9];
    const float* ln2   = (const float*)d_in[10];
    const float* wgp   = (const float*)d_in[11];
    const float* wup   = (const float*)d_in[12];
    const float* wdp   = (const float*)d_in[13];
    const void*  mask  = d_in[14];
    float* dout = (float*)d_out;
    char* ws = (char*)d_ws;
    const size_t MB = (size_t)1 << 20;

    unsigned short* winh  = (unsigned short*)(ws + 0 * MB);
    unsigned short* winl  = (unsigned short*)(ws + 2 * MB);
    unsigned short* weffb = (unsigned short*)(ws + 4 * MB);
    unsigned short* gatewb= (unsigned short*)(ws + 6 * MB);
    unsigned short* wgb   = (unsigned short*)(ws + 8 * MB);
    unsigned short* wub   = (unsigned short*)(ws + 24 * MB);
    unsigned short* wdb   = (unsigned short*)(ws + 40 * MB);
    unsigned short* ahi   = (unsigned short*)(ws + 56 * MB);   // reused as y_bf
    unsigned short* alo   = (unsigned short*)(ws + 72 * MB);
    float*          Ubuf  = (float*)(ws + 88 * MB);            // reused as hff chunk
    unsigned short* hffb  = (unsigned short*)(ws + 88 * MB);
    unsigned short* sbf   = (unsigned short*)(ws + 120 * MB);
    float*          x2    = (float*)(ws + 136 * MB);
    float*          hgb   = (float*)(ws + 168 * MB);           // 32 KB
    int*            flags = (int*)(ws + 168 * MB + 64 * 1024); // 128 B
    int*            flag  = (int*)(ws + 168 * MB + 80 * 1024);
    unsigned int*   spk   = (unsigned int*)(ws + 169 * MB);    // 1 MB

    hipMemsetAsync(flags, 0, 512, stream);
    maskprobe_k<<<1, 256, 0, stream>>>((const unsigned int*)mask, flag);
    weff_k<<<1024, 256, 0, stream>>>(synw, mask, flag, weffb);
    split_k<<<1024, 256, 0, stream>>>(win, winh, winl, DIM * DIM);
    conv_k<<<1024, 256, 0, stream>>>(gatew, gatewb, DIM * DIM);
    conv_k<<<2048, 256, 0, stream>>>(wgp, wgb, HFF * DIM);
    conv_k<<<2048, 256, 0, stream>>>(wup, wub, HFF * DIM);
    conv_k<<<2048, 256, 0, stream>>>(wdp, wdb, DIM * HFF);

    rms_k<true><<<NBATCH * TT, 256, 0, stream>>>(x, ln1, ahi, alo);
    gemm_k<0><<<dim3(DIM / 128, (NBATCH * TT) / 128), 256, 0, stream>>>(
        ahi, alo, winh, winl, nullptr, liqb, nullptr, Ubuf, nullptr,
        NBATCH * TT, DIM, DIM);

    recur_k<<<PWG, 512, 0, stream>>>(wrec, Ubuf, liqtau, plifw, hgb, flags, spk);
    spkexp_k<<<(NBATCH * 64 * 1024) / 256, 256, 0, stream>>>(spk, sbf);

    gemm_k<1><<<dim3(DIM / 128, (NBATCH * TT) / 128), 256, 0, stream>>>(
        sbf, nullptr, weffb, nullptr, gatewb, x, gateb, x2, nullptr,
        NBATCH * TT, DIM, DIM);

    rms_k<false><<<NBATCH * TT, 256, 0, stream>>>(x2, ln2, ahi, nullptr);

    const int CH = 2048;  // FFN row-chunk to bound hff scratch to 32 MB
    for (int c = 0; c < (NBATCH * TT) / CH; ++c) {
        const size_t ro = (size_t)c * CH;
        gemm_k<2><<<dim3(HFF / 128, CH / 128), 256, 0, stream>>>(
            ahi + ro * DIM, nullptr, wgb, nullptr, wub, nullptr, nullptr,
            nullptr, hffb, CH, HFF, DIM);
        gemm_k<3><<<dim3(DIM / 128, CH / 128), 256, 0, stream>>>(
            hffb, nullptr, wdb, nullptr, nullptr, x2 + ro * DIM, nullptr,
            dout + ro * DIM, nullptr, CH, DIM, HFF);
    }
}